// Round 17
// baseline (722.388 us; speedup 1.0000x reference)
//
#include <hip/hip_runtime.h>

using bf16x8 = __attribute__((ext_vector_type(8))) short;
using f32x4  = __attribute__((ext_vector_type(4))) float;

#define DEV static __device__ __forceinline__

constexpr int SEQ    = 1040;
constexpr int MDIM   = 2048;
constexpr int NH     = 16;
constexpr int HD     = 128;
constexpr int NCACHE = 8320;
constexpr int LTOT   = NCACHE + SEQ;   // 9360
constexpr int NQT    = 17;             // ceil(SEQ/64)  (fallback kernel)
constexpr int NQT2   = 9;              // ceil(SEQ/128)

DEV float b2f(unsigned short u) {
  union { unsigned int i; float f; } z; z.i = ((unsigned int)u) << 16; return z.f;
}
DEV unsigned short f2b(float f) {
  union { float f; unsigned int i; } z; z.f = f;
  return (unsigned short)((z.i + 0x7fffu + ((z.i >> 16) & 1u)) >> 16);
}
DEV unsigned int cvtpk(float lo, float hi) {
  unsigned int r;
  asm("v_cvt_pk_bf16_f32 %0, %1, %2" : "=v"(r) : "v"(lo), "v"(hi));
  return r;
}
union U4S8 { uint4 u; short s[8]; };
union F4U4 { f32x4 f; uint4 u; };

// ---------- fused QKV GEMM: N = 6144, grid (48, 9) (unchanged, passing) ----------
__global__ __launch_bounds__(256) void gemm_qkv_k(
    const float* __restrict__ x,
    const float* __restrict__ Wq, const float* __restrict__ Wk, const float* __restrict__ Wv,
    const float* __restrict__ bq, const float* __restrict__ bk, const float* __restrict__ bv,
    unsigned short* __restrict__ Qb, unsigned short* __restrict__ Kn, unsigned short* __restrict__ Vn) {
  __shared__ short As[128][40];
  __shared__ short Bs[128][40];
  const int tid = threadIdx.x;
  const int l = tid & 63, wv = tid >> 6;
  const int l16 = l & 15, kl = l >> 4;
  const int m0 = blockIdx.y * 128;
  const int n0g = blockIdx.x * 128;
  const int which = n0g >> 11;
  const int n0 = n0g & 2047;
  const float* W = (which == 0) ? Wq : (which == 1) ? Wk : Wv;
  const float* bias = (which == 0) ? bq : (which == 1) ? bk : bv;
  unsigned short* outp = (which == 0) ? Qb : (which == 1) ? Kn : Vn;
  const int wm = (wv >> 1) * 64, wn = (wv & 1) * 64;
  const int nq = tid >> 4, kh = tid & 15;
  f32x4 acc[4][4] = {};
  for (int k0 = 0; k0 < MDIM; k0 += 32) {
#pragma unroll
    for (int it = 0; it < 2; ++it) {
      int slot = tid + it * 256;
      int m = slot >> 2, kq = slot & 3;
      int row = m0 + m, k = k0 + kq * 8;
      U4S8 v; v.u = make_uint4(0, 0, 0, 0);
      if (row < SEQ) {
        const float* Af = x + (size_t)row * MDIM + k;
        f32x4 f0 = *(const f32x4*)(Af);
        f32x4 f1 = *(const f32x4*)(Af + 4);
        v.u = make_uint4(cvtpk(f0[0], f0[1]), cvtpk(f0[2], f0[3]),
                         cvtpk(f1[0], f1[1]), cvtpk(f1[2], f1[3]));
      }
      *(uint4*)&As[m][kq * 8] = v.u;
    }
    {
      const float* Wp = W + (size_t)(k0 + kh * 2) * MDIM + n0 + nq * 8;
      f32x4 a0 = *(const f32x4*)(Wp);
      f32x4 a1 = *(const f32x4*)(Wp + 4);
      f32x4 b0 = *(const f32x4*)(Wp + MDIM);
      f32x4 b1 = *(const f32x4*)(Wp + MDIM + 4);
#pragma unroll
      for (int i = 0; i < 4; ++i) {
        *(unsigned int*)&Bs[nq * 8 + i][kh * 2] = cvtpk(a0[i], b0[i]);
        *(unsigned int*)&Bs[nq * 8 + 4 + i][kh * 2] = cvtpk(a1[i], b1[i]);
      }
    }
    __syncthreads();
    bf16x8 aF[4], bF[4];
#pragma unroll
    for (int mi = 0; mi < 4; ++mi)
      aF[mi] = *(const bf16x8*)&As[wm + mi * 16 + l16][kl * 8];
#pragma unroll
    for (int ni = 0; ni < 4; ++ni)
      bF[ni] = *(const bf16x8*)&Bs[wn + ni * 16 + l16][kl * 8];
#pragma unroll
    for (int mi = 0; mi < 4; ++mi)
#pragma unroll
      for (int ni = 0; ni < 4; ++ni)
        acc[mi][ni] = __builtin_amdgcn_mfma_f32_16x16x32_bf16(
            aF[mi], bF[ni], acc[mi][ni], 0, 0, 0);
    __syncthreads();
  }
#pragma unroll
  for (int ni = 0; ni < 4; ++ni) {
    const int col = n0 + wn + ni * 16 + l16;
    const float bb = bias[col];
#pragma unroll
    for (int mi = 0; mi < 4; ++mi) {
      const int rowb = m0 + wm + mi * 16 + kl * 4;
#pragma unroll
      for (int r = 0; r < 4; ++r) {
        const int row = rowb + r;
        if (row >= SEQ) continue;
        outp[((size_t)(col >> 7) * SEQ + row) * HD + (col & 127)] = f2b(acc[mi][ni][r] + bb);
      }
    }
  }
}

// ---------- GEMM for Wo (unchanged, passing) ----------
__global__ __launch_bounds__(256) void gemm_k(
    const void* __restrict__ Ap, const float* __restrict__ W,
    const float* __restrict__ bias, void* __restrict__ outp,
    int aLay, int oMode) {
  __shared__ short As[128][40];
  __shared__ short Bs[128][40];
  const int tid = threadIdx.x;
  const int l = tid & 63, wv = tid >> 6;
  const int l16 = l & 15, kl = l >> 4;
  const int m0 = blockIdx.y * 128, n0 = blockIdx.x * 128;
  const int wm = (wv >> 1) * 64, wn = (wv & 1) * 64;
  const int nq = tid >> 4, kh = tid & 15;
  f32x4 acc[4][4] = {};
  for (int k0 = 0; k0 < MDIM; k0 += 32) {
#pragma unroll
    for (int it = 0; it < 2; ++it) {
      int slot = tid + it * 256;
      int m = slot >> 2, kq = slot & 3;
      int row = m0 + m, k = k0 + kq * 8;
      bf16x8 v = {0, 0, 0, 0, 0, 0, 0, 0};
      if (row < SEQ) {
        if (aLay == 0) {
          const float* Af = (const float*)Ap + (size_t)row * MDIM + k;
          f32x4 f0 = *(const f32x4*)(Af);
          f32x4 f1 = *(const f32x4*)(Af + 4);
          U4S8 u; u.u = make_uint4(cvtpk(f0[0], f0[1]), cvtpk(f0[2], f0[3]),
                                   cvtpk(f1[0], f1[1]), cvtpk(f1[2], f1[3]));
#pragma unroll
          for (int i = 0; i < 8; ++i) v[i] = u.s[i];
        } else {
          const unsigned short* Ab = (const unsigned short*)Ap;
          v = *(const bf16x8*)(Ab + ((size_t)(k >> 7) * SEQ + row) * HD + (k & 127));
        }
      }
      *(bf16x8*)&As[m][kq * 8] = v;
    }
    {
      const float* Wp = W + (size_t)(k0 + kh * 2) * MDIM + n0 + nq * 8;
      f32x4 a0 = *(const f32x4*)(Wp);
      f32x4 a1 = *(const f32x4*)(Wp + 4);
      f32x4 b0 = *(const f32x4*)(Wp + MDIM);
      f32x4 b1 = *(const f32x4*)(Wp + MDIM + 4);
#pragma unroll
      for (int i = 0; i < 4; ++i) {
        *(unsigned int*)&Bs[nq * 8 + i][kh * 2] = cvtpk(a0[i], b0[i]);
        *(unsigned int*)&Bs[nq * 8 + 4 + i][kh * 2] = cvtpk(a1[i], b1[i]);
      }
    }
    __syncthreads();
    bf16x8 aF[4], bF[4];
#pragma unroll
    for (int mi = 0; mi < 4; ++mi)
      aF[mi] = *(const bf16x8*)&As[wm + mi * 16 + l16][kl * 8];
#pragma unroll
    for (int ni = 0; ni < 4; ++ni)
      bF[ni] = *(const bf16x8*)&Bs[wn + ni * 16 + l16][kl * 8];
#pragma unroll
    for (int mi = 0; mi < 4; ++mi)
#pragma unroll
      for (int ni = 0; ni < 4; ++ni)
        acc[mi][ni] = __builtin_amdgcn_mfma_f32_16x16x32_bf16(
            aF[mi], bF[ni], acc[mi][ni], 0, 0, 0);
    __syncthreads();
  }
#pragma unroll
  for (int ni = 0; ni < 4; ++ni) {
    const int col = n0 + wn + ni * 16 + l16;
    const float bb = bias[col];
#pragma unroll
    for (int mi = 0; mi < 4; ++mi) {
      const int rowb = m0 + wm + mi * 16 + kl * 4;
#pragma unroll
      for (int r = 0; r < 4; ++r) {
        const int row = rowb + r;
        if (row >= SEQ) continue;
        const float val = acc[mi][ni][r] + bb;
        if (oMode == 2) {
          ((unsigned short*)outp)[((size_t)(col >> 7) * SEQ + row) * HD + (col & 127)] = f2b(val);
        } else {
          ((float*)outp)[(size_t)row * MDIM + col] = val;
        }
      }
    }
  }
}

// ---------- RMSNorm + RoPE (unchanged, passing) ----------
__global__ __launch_bounds__(256) void rmsrope_k(
    unsigned short* __restrict__ Qb, unsigned short* __restrict__ Kn,
    const float* __restrict__ gq, const float* __restrict__ gk,
    const float* __restrict__ fr) {
  const int s = blockIdx.x, which = blockIdx.y;
  unsigned short* B = which ? Kn : Qb;
  const float* g = which ? gk : gq;
  __shared__ float cs[64], sn[64], red[4];
  const int t = threadIdx.x;
  if (t < 64) {
    float a = fr[s * 64 + t];
    cs[t] = cosf(a);
    sn[t] = sinf(a);
  }
  const int c0 = t * 8;
  const int hh = c0 >> 7, dd = c0 & 127, p0 = dd >> 1;
  const size_t addr = ((size_t)hh * SEQ + s) * HD + dd;
  bf16x8 v = *(const bf16x8*)(B + addr);
  float y[8];
#pragma unroll
  for (int i = 0; i < 8; ++i) y[i] = b2f((unsigned short)v[i]);
  float ssq = 0.f;
#pragma unroll
  for (int i = 0; i < 8; ++i) ssq += y[i] * y[i];
#pragma unroll
  for (int off = 32; off; off >>= 1) ssq += __shfl_xor(ssq, off);
  if ((t & 63) == 0) red[t >> 6] = ssq;
  __syncthreads();
  const float var = (red[0] + red[1] + red[2] + red[3]) * (1.0f / MDIM);
  const float rs = rsqrtf(var + 1e-6f);
  bf16x8 ov;
#pragma unroll
  for (int i = 0; i < 4; ++i) {
    float e = b2f(f2b(y[2 * i] * rs)) * g[c0 + 2 * i];
    float o = b2f(f2b(y[2 * i + 1] * rs)) * g[c0 + 2 * i + 1];
    float C = cs[p0 + i], S = sn[p0 + i];
    ov[2 * i]     = (short)f2b(e * C - o * S);
    ov[2 * i + 1] = (short)f2b(e * S + o * C);
  }
  *(bf16x8*)(B + addr) = ov;
}

// ---------- flash attention v4: r15 structure (UN alias, 36.9KB LDS, 4 barriers)
//            + ONLY T14 register prefetch added ----------
__global__ __launch_bounds__(512) void attn_part4_k(
    const unsigned short* __restrict__ Qb, const unsigned short* __restrict__ Kn,
    const unsigned short* __restrict__ Vn, const float* __restrict__ Kc,
    const float* __restrict__ Vc, float* __restrict__ Opart,
    float* __restrict__ ml, int chunk, int S) {
  __shared__ short UN[9216];        // Kl: UN[j*136+d] ; Pl: UN[(w*16+r)*72+c] (aliased)
  __shared__ short Vt[128][72];
  const int b = blockIdx.x;
  const int xcd = b & 7;
  const int r_ = b >> 3;
  const int qt = r_ % NQT2;
  const int g = (r_ / NQT2) * 8 + xcd;   // group id = z*NH + h
  const int h = g & (NH - 1);
  const int z = g >> 4;
  const int tid = threadIdx.x, wv = tid >> 6, l = tid & 63;
  const int l16 = l & 15, kl = l >> 4;
  const float SCALE = 0.08838834764831845f;

  const int c0 = z * chunk;
  const int cend = min(c0 + chunk, LTOT);

  int qrow = qt * 128 + wv * 16 + l16;
  if (qrow > SEQ - 1) qrow = SEQ - 1;
  bf16x8 qf[4];
#pragma unroll
  for (int kk = 0; kk < 4; ++kk)
    qf[kk] = *(const bf16x8*)(Qb + ((size_t)h * SEQ + qrow) * HD + kk * 32 + kl * 8);

  // T14 prefetch registers (raw K/V of the NEXT tile)
  F4U4 kr[2][2], vr[2][2];
  const int j0 = tid & 63, dq0 = tid >> 6;          // it=0 slot
  const int dq1 = (tid + 512) >> 6;                 // it=1 slot (same j)

  auto LOADREGS = [&](int kv) {
#pragma unroll
    for (int it = 0; it < 2; ++it) {
      const int dq = (it == 0) ? dq0 : dq1;
      const int jg = kv + j0;
      F4U4 a0, a1, b0, b1;
      a0.u = make_uint4(0, 0, 0, 0); a1.u = make_uint4(0, 0, 0, 0);
      b0.u = make_uint4(0, 0, 0, 0); b1.u = make_uint4(0, 0, 0, 0);
      if (jg < NCACHE) {
        const float* kp = Kc + ((size_t)jg * NH + h) * HD + dq * 8;
        const float* vp = Vc + ((size_t)jg * NH + h) * HD + dq * 8;
        a0.f = *(const f32x4*)(kp); a1.f = *(const f32x4*)(kp + 4);
        b0.f = *(const f32x4*)(vp); b1.f = *(const f32x4*)(vp + 4);
      } else if (jg < LTOT) {
        a0.u = *(const uint4*)(Kn + ((size_t)h * SEQ + (jg - NCACHE)) * HD + dq * 8);
        b0.u = *(const uint4*)(Vn + ((size_t)h * SEQ + (jg - NCACHE)) * HD + dq * 8);
      }
      kr[it][0] = a0; kr[it][1] = a1;
      vr[it][0] = b0; vr[it][1] = b1;
    }
  };

  auto WRITELDS = [&](int kv) {
#pragma unroll
    for (int it = 0; it < 2; ++it) {
      const int dq = (it == 0) ? dq0 : dq1;
      const int jg = kv + j0;
      U4S8 ku, vu;
      if (jg < NCACHE) {
        ku.u = make_uint4(cvtpk(kr[it][0].f[0], kr[it][0].f[1]), cvtpk(kr[it][0].f[2], kr[it][0].f[3]),
                          cvtpk(kr[it][1].f[0], kr[it][1].f[1]), cvtpk(kr[it][1].f[2], kr[it][1].f[3]));
        vu.u = make_uint4(cvtpk(vr[it][0].f[0], vr[it][0].f[1]), cvtpk(vr[it][0].f[2], vr[it][0].f[3]),
                          cvtpk(vr[it][1].f[0], vr[it][1].f[1]), cvtpk(vr[it][1].f[2], vr[it][1].f[3]));
      } else {
        ku.u = kr[it][0].u;
        vu.u = vr[it][0].u;
      }
      *(uint4*)&UN[j0 * 136 + dq * 8] = ku.u;
#pragma unroll
      for (int i = 0; i < 8; ++i) Vt[dq * 8 + i][j0] = vu.s[i];
    }
  };

  f32x4 oacc[8] = {};
  float mrow[4] = {-1e30f, -1e30f, -1e30f, -1e30f};
  float lrow[4] = {0.f, 0.f, 0.f, 0.f};

  LOADREGS(c0);   // prologue

  for (int kv0 = c0; kv0 < cend; kv0 += 64) {
    WRITELDS(kv0);
    __syncthreads();                                   // bar1: K/V staged
    if (kv0 + 64 < cend) LOADREGS(kv0 + 64);           // T14: issue next-tile loads

    // ---- S = Q K^T (reads UN as Kl)
    f32x4 sa[4] = {};
#pragma unroll
    for (int ni = 0; ni < 4; ++ni)
#pragma unroll
      for (int kk = 0; kk < 4; ++kk) {
        bf16x8 bK = *(const bf16x8*)&UN[(ni * 16 + l16) * 136 + kk * 32 + kl * 8];
        sa[ni] = __builtin_amdgcn_mfma_f32_16x16x32_bf16(qf[kk], bK, sa[ni], 0, 0, 0);
      }
    __syncthreads();                                   // bar2: QK reads done (Pl aliases Kl)

    // ---- online softmax (registers only)
    float sv[4][4];
    float pm[4] = {-1e30f, -1e30f, -1e30f, -1e30f};
#pragma unroll
    for (int ni = 0; ni < 4; ++ni) {
      int jg = kv0 + ni * 16 + l16;
      bool valid = jg < LTOT;
#pragma unroll
      for (int r = 0; r < 4; ++r) {
        float xs = valid ? sa[ni][r] * SCALE : -1e30f;
        sv[ni][r] = xs;
        pm[r] = fmaxf(pm[r], xs);
      }
    }
#pragma unroll
    for (int off = 1; off < 16; off <<= 1)
#pragma unroll
      for (int r = 0; r < 4; ++r) pm[r] = fmaxf(pm[r], __shfl_xor(pm[r], off));

    float sc[4];
#pragma unroll
    for (int r = 0; r < 4; ++r) {
      float mn = fmaxf(mrow[r], pm[r]);
      sc[r] = __expf(mrow[r] - mn);
      mrow[r] = mn;
    }
    float ps[4] = {0.f, 0.f, 0.f, 0.f};
#pragma unroll
    for (int ni = 0; ni < 4; ++ni)
#pragma unroll
      for (int r = 0; r < 4; ++r) {
        float p = __expf(sv[ni][r] - mrow[r]);
        sv[ni][r] = p;
        ps[r] += p;
      }
#pragma unroll
    for (int off = 1; off < 16; off <<= 1)
#pragma unroll
      for (int r = 0; r < 4; ++r) ps[r] += __shfl_xor(ps[r], off);
#pragma unroll
    for (int r = 0; r < 4; ++r) lrow[r] = lrow[r] * sc[r] + ps[r];
#pragma unroll
    for (int di = 0; di < 8; ++di)
#pragma unroll
      for (int r = 0; r < 4; ++r) oacc[di][r] *= sc[r];
    // ---- write P into UN (Pl region)
#pragma unroll
    for (int ni = 0; ni < 4; ++ni)
#pragma unroll
      for (int r = 0; r < 4; ++r)
        UN[(wv * 16 + kl * 4 + r) * 72 + ni * 16 + l16] = (short)f2b(sv[ni][r]);
    __syncthreads();                                   // bar3: P staged

    // ---- O += P V
#pragma unroll
    for (int di = 0; di < 8; ++di)
#pragma unroll
      for (int k2 = 0; k2 < 2; ++k2) {
        bf16x8 aP = *(const bf16x8*)&UN[(wv * 16 + l16) * 72 + k2 * 32 + kl * 8];
        bf16x8 bV = *(const bf16x8*)&Vt[di * 16 + l16][k2 * 32 + kl * 8];
        oacc[di] = __builtin_amdgcn_mfma_f32_16x16x32_bf16(aP, bV, oacc[di], 0, 0, 0);
      }
    __syncthreads();                                   // bar4: PV done before next write
  }

  const size_t pbase = (((size_t)z * NH + h) * NQT2 + qt);
  const int row = wv * 16 + kl * 4;
#pragma unroll
  for (int r = 0; r < 4; ++r) {
    float* Op = Opart + (pbase * 128 + row + r) * HD;
#pragma unroll
    for (int di = 0; di < 8; ++di) Op[di * 16 + l16] = oacc[di][r];
    ml[(pbase * 2 + 0) * 128 + row + r] = mrow[r];
    ml[(pbase * 2 + 1) * 128 + row + r] = lrow[r];
  }
}

// ---------- merge partials (QBLK=128) -> bf16 O in Qb (unchanged, passing) ----------
__global__ __launch_bounds__(512) void attn_merge2_k(
    const float* __restrict__ Opart, const float* __restrict__ ml,
    unsigned short* __restrict__ Qb, int S) {
  const int qt = blockIdx.x, h = blockIdx.y;
  const int t = threadIdx.x;
  const int row = t >> 2, d0 = (t & 3) * 32;
  const int q = qt * 128 + row;

  float M = -1e30f;
  for (int s = 0; s < S; ++s) {
    const size_t pbase = (((size_t)s * NH + h) * NQT2 + qt);
    M = fmaxf(M, ml[(pbase * 2 + 0) * 128 + row]);
  }
  float L = 0.f;
  float o[32];
#pragma unroll
  for (int i = 0; i < 32; ++i) o[i] = 0.f;
  for (int s = 0; s < S; ++s) {
    const size_t pbase = (((size_t)s * NH + h) * NQT2 + qt);
    const float ms = ml[(pbase * 2 + 0) * 128 + row];
    const float ls = ml[(pbase * 2 + 1) * 128 + row];
    const float w = __expf(ms - M);
    L += w * ls;
    const float* Op = Opart + (pbase * 128 + row) * HD + d0;
#pragma unroll
    for (int c = 0; c < 8; ++c) {
      f32x4 v = *(const f32x4*)(Op + c * 4);
#pragma unroll
      for (int i = 0; i < 4; ++i) o[c * 4 + i] += w * v[i];
    }
  }
  if (q < SEQ) {
    const float inv = 1.f / L;
    unsigned short* op = Qb + ((size_t)h * SEQ + q) * HD + d0;
#pragma unroll
    for (int i = 0; i < 32; ++i) op[i] = f2b(o[i] * inv);
  }
}

// ---------- fallback single-pass attention (known-passing, untouched) ----------
__global__ __launch_bounds__(256) void attn_k(
    unsigned short* __restrict__ Qb, const unsigned short* __restrict__ Kn,
    const unsigned short* __restrict__ Vn, const float* __restrict__ Kc,
    const float* __restrict__ Vc) {
  __shared__ short Kl[64][136];
  __shared__ short Vt[128][72];
  __shared__ short Pl[4][16][72];
  const int h = blockIdx.y, qt = blockIdx.x;
  const int tid = threadIdx.x, wv = tid >> 6, l = tid & 63;
  const int l16 = l & 15, kl = l >> 4;
  const float SCALE = 0.08838834764831845f;

  int qrow = qt * 64 + wv * 16 + l16;
  if (qrow > SEQ - 1) qrow = SEQ - 1;
  bf16x8 qf[4];
#pragma unroll
  for (int kk = 0; kk < 4; ++kk)
    qf[kk] = *(const bf16x8*)(Qb + ((size_t)h * SEQ + qrow) * HD + kk * 32 + kl * 8);

  f32x4 oacc[8] = {};
  float mrow[4] = {-1e30f, -1e30f, -1e30f, -1e30f};
  float lrow[4] = {0.f, 0.f, 0.f, 0.f};

  for (int kv0 = 0; kv0 < LTOT; kv0 += 64) {
#pragma unroll
    for (int it = 0; it < 4; ++it) {
      int slot = tid + it * 256;
      int j = slot & 63, dq = slot >> 6;
      int jg = kv0 + j;
      bf16x8 kvv = {0,0,0,0,0,0,0,0}, vvv = {0,0,0,0,0,0,0,0};
      if (jg < NCACHE) {
        const float* kp = Kc + ((size_t)jg * NH + h) * HD + dq * 8;
        const float* vp = Vc + ((size_t)jg * NH + h) * HD + dq * 8;
        f32x4 ka = *(const f32x4*)(kp), kb = *(const f32x4*)(kp + 4);
        f32x4 va = *(const f32x4*)(vp), vb = *(const f32x4*)(vp + 4);
#pragma unroll
        for (int i = 0; i < 4; ++i) {
          kvv[i] = (short)f2b(ka[i]); kvv[4 + i] = (short)f2b(kb[i]);
          vvv[i] = (short)f2b(va[i]); vvv[4 + i] = (short)f2b(vb[i]);
        }
      } else if (jg < LTOT) {
        kvv = *(const bf16x8*)(Kn + ((size_t)h * SEQ + (jg - NCACHE)) * HD + dq * 8);
        vvv = *(const bf16x8*)(Vn + ((size_t)h * SEQ + (jg - NCACHE)) * HD + dq * 8);
      }
      *(bf16x8*)&Kl[j][dq * 8] = kvv;
#pragma unroll
      for (int i = 0; i < 8; ++i) Vt[dq * 8 + i][j] = vvv[i];
    }
    __syncthreads();

    f32x4 sa[4] = {};
#pragma unroll
    for (int ni = 0; ni < 4; ++ni)
#pragma unroll
      for (int kk = 0; kk < 4; ++kk) {
        bf16x8 bK = *(const bf16x8*)&Kl[ni * 16 + l16][kk * 32 + kl * 8];
        sa[ni] = __builtin_amdgcn_mfma_f32_16x16x32_bf16(qf[kk], bK, sa[ni], 0, 0, 0);
      }

    float sv[4][4];
    float pm[4] = {-1e30f, -1e30f, -1e30f, -1e30f};
#pragma unroll
    for (int ni = 0; ni < 4; ++ni) {
      int jg = kv0 + ni * 16 + l16;
      bool valid = jg < LTOT;
#pragma unroll
      for (int r = 0; r < 4; ++r) {
        float xs = valid ? sa[ni][r] * SCALE : -1e30f;
        sv[ni][r] = xs;
        pm[r] = fmaxf(pm[r], xs);
      }
    }
#pragma unroll
    for (int off = 1; off < 16; off <<= 1)
#pragma unroll
      for (int r = 0; r < 4; ++r) pm[r] = fmaxf(pm[r], __shfl_xor(pm[r], off));

    float sc[4];
#pragma unroll
    for (int r = 0; r < 4; ++r) {
      float mn = fmaxf(mrow[r], pm[r]);
      sc[r] = __expf(mrow[r] - mn);
      mrow[r] = mn;
    }
    float ps[4] = {0.f, 0.f, 0.f, 0.f};
#pragma unroll
    for (int ni = 0; ni < 4; ++ni)
#pragma unroll
      for (int r = 0; r < 4; ++r) {
        float p = __expf(sv[ni][r] - mrow[r]);
        sv[ni][r] = p;
        ps[r] += p;
      }
#pragma unroll
    for (int off = 1; off < 16; off <<= 1)
#pragma unroll
      for (int r = 0; r < 4; ++r) ps[r] += __shfl_xor(ps[r], off);
#pragma unroll
    for (int r = 0; r < 4; ++r) lrow[r] = lrow[r] * sc[r] + ps[r];
#pragma unroll
    for (int di = 0; di < 8; ++di)
#pragma unroll
      for (int r = 0; r < 4; ++r) oacc[di][r] *= sc[r];
#pragma unroll
    for (int ni = 0; ni < 4; ++ni)
#pragma unroll
      for (int r = 0; r < 4; ++r)
        Pl[wv][kl * 4 + r][ni * 16 + l16] = (short)f2b(sv[ni][r]);
    __syncthreads();

#pragma unroll
    for (int di = 0; di < 8; ++di)
#pragma unroll
      for (int k2 = 0; k2 < 2; ++k2) {
        bf16x8 aP = *(const bf16x8*)&Pl[wv][l16][k2 * 32 + kl * 8];
        bf16x8 bV = *(const bf16x8*)&Vt[di * 16 + l16][k2 * 32 + kl * 8];
        oacc[di] = __builtin_amdgcn_mfma_f32_16x16x32_bf16(aP, bV, oacc[di], 0, 0, 0);
      }
    __syncthreads();
  }

  const int qb = qt * 64 + wv * 16 + kl * 4;
#pragma unroll
  for (int r = 0; r < 4; ++r) {
    int q = qb + r;
    if (q < SEQ) {
      float inv = 1.0f / lrow[r];
#pragma unroll
      for (int di = 0; di < 8; ++di)
        Qb[((size_t)h * SEQ + q) * HD + di * 16 + l16] = f2b(oacc[di][r] * inv);
    }
  }
}

extern "C" void kernel_launch(void* const* d_in, const int* in_sizes, int n_in,
                              void* d_out, int out_size, void* d_ws, size_t ws_size,
                              hipStream_t stream) {
  const float* x  = (const float*)d_in[0];
  const float* fr = (const float*)d_in[2];
  const float* Kc = (const float*)d_in[3];
  const float* Vc = (const float*)d_in[4];
  const float* Wq = (const float*)d_in[5];
  const float* bq = (const float*)d_in[6];
  const float* Wk = (const float*)d_in[7];
  const float* bk = (const float*)d_in[8];
  const float* Wv = (const float*)d_in[9];
  const float* bv = (const float*)d_in[10];
  const float* Wo = (const float*)d_in[11];
  const float* bo = (const float*)d_in[12];
  const float* gq = (const float*)d_in[13];
  const float* gk = (const float*)d_in[14];

  unsigned short* Qb = (unsigned short*)d_ws;
  unsigned short* Kn = Qb + (size_t)NH * SEQ * HD;
  unsigned short* Vn = Kn + (size_t)NH * SEQ * HD;
  const size_t baseB = (size_t)3 * NH * SEQ * HD * 2;

  const size_t perSplitB = (size_t)NH * NQT2 * 128 * HD * 4
                         + (size_t)NH * NQT2 * 2 * 128 * 4;
  int S = 0;
  if (ws_size >= baseB + 8 * perSplitB + (1 << 20)) S = 8;
  else if (ws_size >= baseB + 7 * perSplitB + (1 << 20)) S = 7;
  else if (ws_size >= baseB + 4 * perSplitB + (1 << 20)) S = 4;

  gemm_qkv_k<<<dim3(48, 9), 256, 0, stream>>>(x, Wq, Wk, Wv, bq, bk, bv, Qb, Kn, Vn);
  rmsrope_k<<<dim3(SEQ, 2), 256, 0, stream>>>(Qb, Kn, gq, gk, fr);

  if (S > 0) {
    float* Opart = (float*)((char*)d_ws + baseB);
    float* ml    = Opart + (size_t)S * NH * NQT2 * 128 * HD;
    const int tiles = (LTOT + 63) / 64;                // 147
    const int chunk = ((tiles + S - 1) / S) * 64;
    attn_part4_k<<<dim3(NQT2 * NH * S), 512, 0, stream>>>(Qb, Kn, Vn, Kc, Vc, Opart, ml, chunk, S);
    attn_merge2_k<<<dim3(NQT2, NH), 512, 0, stream>>>(Opart, ml, Qb, S);
  } else {
    attn_k<<<dim3(NQT, NH), 256, 0, stream>>>(Qb, Kn, Vn, Kc, Vc);
  }

  gemm_k<<<dim3(16, 9), 256, 0, stream>>>(Qb, Wo, bo, d_out, 1, 3);
}

// Round 18
// 517.897 us; speedup vs baseline: 1.3948x; 1.3948x over previous
//
#include <hip/hip_runtime.h>

using bf16x8 = __attribute__((ext_vector_type(8))) short;
using f32x4  = __attribute__((ext_vector_type(4))) float;

#define DEV static __device__ __forceinline__

constexpr int SEQ    = 1040;
constexpr int MDIM   = 2048;
constexpr int NH     = 16;
constexpr int HD     = 128;
constexpr int NCACHE = 8320;
constexpr int LTOT   = NCACHE + SEQ;   // 9360
constexpr int NQT    = 17;             // ceil(SEQ/64)  (fallback kernel)
constexpr int NQT2   = 9;              // ceil(SEQ/128)

DEV float b2f(unsigned short u) {
  union { unsigned int i; float f; } z; z.i = ((unsigned int)u) << 16; return z.f;
}
DEV unsigned short f2b(float f) {
  union { float f; unsigned int i; } z; z.f = f;
  return (unsigned short)((z.i + 0x7fffu + ((z.i >> 16) & 1u)) >> 16);
}
DEV unsigned int cvtpk(float lo, float hi) {
  unsigned int r;
  asm("v_cvt_pk_bf16_f32 %0, %1, %2" : "=v"(r) : "v"(lo), "v"(hi));
  return r;
}
union U4S8 { uint4 u; short s[8]; };

// ---------- fused QKV GEMM v2: 64x128 tiles, grid (48, 17) = 816 blocks ----------
__global__ __launch_bounds__(256) void gemm_qkv_k(
    const float* __restrict__ x,
    const float* __restrict__ Wq, const float* __restrict__ Wk, const float* __restrict__ Wv,
    const float* __restrict__ bq, const float* __restrict__ bk, const float* __restrict__ bv,
    unsigned short* __restrict__ Qb, unsigned short* __restrict__ Kn, unsigned short* __restrict__ Vn) {
  __shared__ short As[64][40];
  __shared__ short Bs[128][40];
  const int tid = threadIdx.x;
  const int l = tid & 63, wv = tid >> 6;
  const int l16 = l & 15, kl = l >> 4;
  const int m0 = blockIdx.y * 64;
  const int n0g = blockIdx.x * 128;
  const int which = n0g >> 11;
  const int n0 = n0g & 2047;
  const float* W = (which == 0) ? Wq : (which == 1) ? Wk : Wv;
  const float* bias = (which == 0) ? bq : (which == 1) ? bk : bv;
  unsigned short* outp = (which == 0) ? Qb : (which == 1) ? Kn : Vn;
  const int wm = (wv >> 1) * 32, wn = (wv & 1) * 64;
  const int nq = tid >> 4, kh = tid & 15;
  f32x4 acc[2][4] = {};
  for (int k0 = 0; k0 < MDIM; k0 += 32) {
    // A tile [64 rows][32 k] : one slot per thread
    {
      int m = tid >> 2, kq = tid & 3;
      int row = m0 + m, k = k0 + kq * 8;
      U4S8 v; v.u = make_uint4(0, 0, 0, 0);
      if (row < SEQ) {
        const float* Af = x + (size_t)row * MDIM + k;
        f32x4 f0 = *(const f32x4*)(Af);
        f32x4 f1 = *(const f32x4*)(Af + 4);
        v.u = make_uint4(cvtpk(f0[0], f0[1]), cvtpk(f0[2], f0[3]),
                         cvtpk(f1[0], f1[1]), cvtpk(f1[2], f1[3]));
      }
      *(uint4*)&As[m][kq * 8] = v.u;
    }
    // B tile transposed: Bs[n][k] = bf16(W[k0+k][n0+n])
    {
      const float* Wp = W + (size_t)(k0 + kh * 2) * MDIM + n0 + nq * 8;
      f32x4 a0 = *(const f32x4*)(Wp);
      f32x4 a1 = *(const f32x4*)(Wp + 4);
      f32x4 b0 = *(const f32x4*)(Wp + MDIM);
      f32x4 b1 = *(const f32x4*)(Wp + MDIM + 4);
#pragma unroll
      for (int i = 0; i < 4; ++i) {
        *(unsigned int*)&Bs[nq * 8 + i][kh * 2] = cvtpk(a0[i], b0[i]);
        *(unsigned int*)&Bs[nq * 8 + 4 + i][kh * 2] = cvtpk(a1[i], b1[i]);
      }
    }
    __syncthreads();
    bf16x8 aF[2], bF[4];
#pragma unroll
    for (int mi = 0; mi < 2; ++mi)
      aF[mi] = *(const bf16x8*)&As[wm + mi * 16 + l16][kl * 8];
#pragma unroll
    for (int ni = 0; ni < 4; ++ni)
      bF[ni] = *(const bf16x8*)&Bs[wn + ni * 16 + l16][kl * 8];
#pragma unroll
    for (int mi = 0; mi < 2; ++mi)
#pragma unroll
      for (int ni = 0; ni < 4; ++ni)
        acc[mi][ni] = __builtin_amdgcn_mfma_f32_16x16x32_bf16(
            aF[mi], bF[ni], acc[mi][ni], 0, 0, 0);
    __syncthreads();
  }
#pragma unroll
  for (int ni = 0; ni < 4; ++ni) {
    const int col = n0 + wn + ni * 16 + l16;
    const float bb = bias[col];
#pragma unroll
    for (int mi = 0; mi < 2; ++mi) {
      const int rowb = m0 + wm + mi * 16 + kl * 4;
#pragma unroll
      for (int r = 0; r < 4; ++r) {
        const int row = rowb + r;
        if (row >= SEQ) continue;
        outp[((size_t)(col >> 7) * SEQ + row) * HD + (col & 127)] = f2b(acc[mi][ni][r] + bb);
      }
    }
  }
}

// ---------- GEMM for Wo v2: 64x128 tiles, grid (16, 17) = 272 blocks ----------
__global__ __launch_bounds__(256) void gemm_k(
    const void* __restrict__ Ap, const float* __restrict__ W,
    const float* __restrict__ bias, void* __restrict__ outp,
    int aLay, int oMode) {
  __shared__ short As[64][40];
  __shared__ short Bs[128][40];
  const int tid = threadIdx.x;
  const int l = tid & 63, wv = tid >> 6;
  const int l16 = l & 15, kl = l >> 4;
  const int m0 = blockIdx.y * 64, n0 = blockIdx.x * 128;
  const int wm = (wv >> 1) * 32, wn = (wv & 1) * 64;
  const int nq = tid >> 4, kh = tid & 15;
  f32x4 acc[2][4] = {};
  for (int k0 = 0; k0 < MDIM; k0 += 32) {
    {
      int m = tid >> 2, kq = tid & 3;
      int row = m0 + m, k = k0 + kq * 8;
      bf16x8 v = {0, 0, 0, 0, 0, 0, 0, 0};
      if (row < SEQ) {
        if (aLay == 0) {
          const float* Af = (const float*)Ap + (size_t)row * MDIM + k;
          f32x4 f0 = *(const f32x4*)(Af);
          f32x4 f1 = *(const f32x4*)(Af + 4);
          U4S8 u; u.u = make_uint4(cvtpk(f0[0], f0[1]), cvtpk(f0[2], f0[3]),
                                   cvtpk(f1[0], f1[1]), cvtpk(f1[2], f1[3]));
#pragma unroll
          for (int i = 0; i < 8; ++i) v[i] = u.s[i];
        } else {
          const unsigned short* Ab = (const unsigned short*)Ap;
          v = *(const bf16x8*)(Ab + ((size_t)(k >> 7) * SEQ + row) * HD + (k & 127));
        }
      }
      *(bf16x8*)&As[m][kq * 8] = v;
    }
    {
      const float* Wp = W + (size_t)(k0 + kh * 2) * MDIM + n0 + nq * 8;
      f32x4 a0 = *(const f32x4*)(Wp);
      f32x4 a1 = *(const f32x4*)(Wp + 4);
      f32x4 b0 = *(const f32x4*)(Wp + MDIM);
      f32x4 b1 = *(const f32x4*)(Wp + MDIM + 4);
#pragma unroll
      for (int i = 0; i < 4; ++i) {
        *(unsigned int*)&Bs[nq * 8 + i][kh * 2] = cvtpk(a0[i], b0[i]);
        *(unsigned int*)&Bs[nq * 8 + 4 + i][kh * 2] = cvtpk(a1[i], b1[i]);
      }
    }
    __syncthreads();
    bf16x8 aF[2], bF[4];
#pragma unroll
    for (int mi = 0; mi < 2; ++mi)
      aF[mi] = *(const bf16x8*)&As[wm + mi * 16 + l16][kl * 8];
#pragma unroll
    for (int ni = 0; ni < 4; ++ni)
      bF[ni] = *(const bf16x8*)&Bs[wn + ni * 16 + l16][kl * 8];
#pragma unroll
    for (int mi = 0; mi < 2; ++mi)
#pragma unroll
      for (int ni = 0; ni < 4; ++ni)
        acc[mi][ni] = __builtin_amdgcn_mfma_f32_16x16x32_bf16(
            aF[mi], bF[ni], acc[mi][ni], 0, 0, 0);
    __syncthreads();
  }
#pragma unroll
  for (int ni = 0; ni < 4; ++ni) {
    const int col = n0 + wn + ni * 16 + l16;
    const float bb = bias[col];
#pragma unroll
    for (int mi = 0; mi < 2; ++mi) {
      const int rowb = m0 + wm + mi * 16 + kl * 4;
#pragma unroll
      for (int r = 0; r < 4; ++r) {
        const int row = rowb + r;
        if (row >= SEQ) continue;
        const float val = acc[mi][ni][r] + bb;
        if (oMode == 2) {
          ((unsigned short*)outp)[((size_t)(col >> 7) * SEQ + row) * HD + (col & 127)] = f2b(val);
        } else {
          ((float*)outp)[(size_t)row * MDIM + col] = val;
        }
      }
    }
  }
}

// ---------- RMSNorm + RoPE (unchanged, passing) ----------
__global__ __launch_bounds__(256) void rmsrope_k(
    unsigned short* __restrict__ Qb, unsigned short* __restrict__ Kn,
    const float* __restrict__ gq, const float* __restrict__ gk,
    const float* __restrict__ fr) {
  const int s = blockIdx.x, which = blockIdx.y;
  unsigned short* B = which ? Kn : Qb;
  const float* g = which ? gk : gq;
  __shared__ float cs[64], sn[64], red[4];
  const int t = threadIdx.x;
  if (t < 64) {
    float a = fr[s * 64 + t];
    cs[t] = cosf(a);
    sn[t] = sinf(a);
  }
  const int c0 = t * 8;
  const int hh = c0 >> 7, dd = c0 & 127, p0 = dd >> 1;
  const size_t addr = ((size_t)hh * SEQ + s) * HD + dd;
  bf16x8 v = *(const bf16x8*)(B + addr);
  float y[8];
#pragma unroll
  for (int i = 0; i < 8; ++i) y[i] = b2f((unsigned short)v[i]);
  float ssq = 0.f;
#pragma unroll
  for (int i = 0; i < 8; ++i) ssq += y[i] * y[i];
#pragma unroll
  for (int off = 32; off; off >>= 1) ssq += __shfl_xor(ssq, off);
  if ((t & 63) == 0) red[t >> 6] = ssq;
  __syncthreads();
  const float var = (red[0] + red[1] + red[2] + red[3]) * (1.0f / MDIM);
  const float rs = rsqrtf(var + 1e-6f);
  bf16x8 ov;
#pragma unroll
  for (int i = 0; i < 4; ++i) {
    float e = b2f(f2b(y[2 * i] * rs)) * g[c0 + 2 * i];
    float o = b2f(f2b(y[2 * i + 1] * rs)) * g[c0 + 2 * i + 1];
    float C = cs[p0 + i], S = sn[p0 + i];
    ov[2 * i]     = (short)f2b(e * C - o * S);
    ov[2 * i + 1] = (short)f2b(e * S + o * C);
  }
  *(bf16x8*)(B + addr) = ov;
}

// ---------- flash attention v2 (r15-exact, 309 µs): QBLK=128, 8 waves, Pl alias Kl ----------
__global__ __launch_bounds__(512) void attn_part2_k(
    const unsigned short* __restrict__ Qb, const unsigned short* __restrict__ Kn,
    const unsigned short* __restrict__ Vn, const float* __restrict__ Kc,
    const float* __restrict__ Vc, float* __restrict__ Opart,
    float* __restrict__ ml, int chunk, int S) {
  __shared__ short UN[9216];        // Kl: UN[j*136+d]; Pl: UN[(w*16+r)*72+c]
  __shared__ short Vt[128][72];
  const int b = blockIdx.x;
  const int xcd = b & 7;
  const int r_ = b >> 3;
  const int qt = r_ % NQT2;
  const int g = (r_ / NQT2) * 8 + xcd;   // group id = z*NH + h
  const int h = g & (NH - 1);
  const int z = g >> 4;
  const int tid = threadIdx.x, wv = tid >> 6, l = tid & 63;
  const int l16 = l & 15, kl = l >> 4;
  const float SCALE = 0.08838834764831845f;

  const int c0 = z * chunk;
  const int cend = min(c0 + chunk, LTOT);

  int qrow = qt * 128 + wv * 16 + l16;
  if (qrow > SEQ - 1) qrow = SEQ - 1;
  bf16x8 qf[4];
#pragma unroll
  for (int kk = 0; kk < 4; ++kk)
    qf[kk] = *(const bf16x8*)(Qb + ((size_t)h * SEQ + qrow) * HD + kk * 32 + kl * 8);

  f32x4 oacc[8] = {};
  float mrow[4] = {-1e30f, -1e30f, -1e30f, -1e30f};
  float lrow[4] = {0.f, 0.f, 0.f, 0.f};

  for (int kv0 = c0; kv0 < cend; kv0 += 64) {
#pragma unroll
    for (int it = 0; it < 2; ++it) {
      int slot = tid + it * 512;
      int j = slot & 63, dq = slot >> 6;
      int jg = kv0 + j;
      U4S8 ku, vu;
      ku.u = make_uint4(0, 0, 0, 0);
      vu.u = make_uint4(0, 0, 0, 0);
      if (jg < NCACHE) {
        const float* kp = Kc + ((size_t)jg * NH + h) * HD + dq * 8;
        const float* vp = Vc + ((size_t)jg * NH + h) * HD + dq * 8;
        f32x4 ka = *(const f32x4*)(kp), kb = *(const f32x4*)(kp + 4);
        f32x4 va = *(const f32x4*)(vp), vb = *(const f32x4*)(vp + 4);
        ku.u = make_uint4(cvtpk(ka[0], ka[1]), cvtpk(ka[2], ka[3]),
                          cvtpk(kb[0], kb[1]), cvtpk(kb[2], kb[3]));
        vu.u = make_uint4(cvtpk(va[0], va[1]), cvtpk(va[2], va[3]),
                          cvtpk(vb[0], vb[1]), cvtpk(vb[2], vb[3]));
      } else if (jg < LTOT) {
        ku.u = *(const uint4*)(Kn + ((size_t)h * SEQ + (jg - NCACHE)) * HD + dq * 8);
        vu.u = *(const uint4*)(Vn + ((size_t)h * SEQ + (jg - NCACHE)) * HD + dq * 8);
      }
      *(uint4*)&UN[j * 136 + dq * 8] = ku.u;
#pragma unroll
      for (int i = 0; i < 8; ++i) Vt[dq * 8 + i][j] = vu.s[i];
    }
    __syncthreads();                                   // bar1: K/V staged

    f32x4 sa[4] = {};
#pragma unroll
    for (int ni = 0; ni < 4; ++ni)
#pragma unroll
      for (int kk = 0; kk < 4; ++kk) {
        bf16x8 bK = *(const bf16x8*)&UN[(ni * 16 + l16) * 136 + kk * 32 + kl * 8];
        sa[ni] = __builtin_amdgcn_mfma_f32_16x16x32_bf16(qf[kk], bK, sa[ni], 0, 0, 0);
      }
    __syncthreads();                                   // bar2: QK reads done (Pl aliases Kl)

    float sv[4][4];
    float pm[4] = {-1e30f, -1e30f, -1e30f, -1e30f};
#pragma unroll
    for (int ni = 0; ni < 4; ++ni) {
      int jg = kv0 + ni * 16 + l16;
      bool valid = jg < LTOT;
#pragma unroll
      for (int r = 0; r < 4; ++r) {
        float xs = valid ? sa[ni][r] * SCALE : -1e30f;
        sv[ni][r] = xs;
        pm[r] = fmaxf(pm[r], xs);
      }
    }
#pragma unroll
    for (int off = 1; off < 16; off <<= 1)
#pragma unroll
      for (int r = 0; r < 4; ++r) pm[r] = fmaxf(pm[r], __shfl_xor(pm[r], off));

    float sc[4];
#pragma unroll
    for (int r = 0; r < 4; ++r) {
      float mn = fmaxf(mrow[r], pm[r]);
      sc[r] = __expf(mrow[r] - mn);
      mrow[r] = mn;
    }
    float ps[4] = {0.f, 0.f, 0.f, 0.f};
#pragma unroll
    for (int ni = 0; ni < 4; ++ni)
#pragma unroll
      for (int r = 0; r < 4; ++r) {
        float p = __expf(sv[ni][r] - mrow[r]);
        sv[ni][r] = p;
        ps[r] += p;
      }
#pragma unroll
    for (int off = 1; off < 16; off <<= 1)
#pragma unroll
      for (int r = 0; r < 4; ++r) ps[r] += __shfl_xor(ps[r], off);
#pragma unroll
    for (int r = 0; r < 4; ++r) lrow[r] = lrow[r] * sc[r] + ps[r];
#pragma unroll
    for (int di = 0; di < 8; ++di)
#pragma unroll
      for (int r = 0; r < 4; ++r) oacc[di][r] *= sc[r];
#pragma unroll
    for (int ni = 0; ni < 4; ++ni)
#pragma unroll
      for (int r = 0; r < 4; ++r)
        UN[(wv * 16 + kl * 4 + r) * 72 + ni * 16 + l16] = (short)f2b(sv[ni][r]);
    __syncthreads();                                   // bar3: P staged

#pragma unroll
    for (int di = 0; di < 8; ++di)
#pragma unroll
      for (int k2 = 0; k2 < 2; ++k2) {
        bf16x8 aP = *(const bf16x8*)&UN[(wv * 16 + l16) * 72 + k2 * 32 + kl * 8];
        bf16x8 bV = *(const bf16x8*)&Vt[di * 16 + l16][k2 * 32 + kl * 8];
        oacc[di] = __builtin_amdgcn_mfma_f32_16x16x32_bf16(aP, bV, oacc[di], 0, 0, 0);
      }
    __syncthreads();                                   // bar4
  }

  const size_t pbase = (((size_t)z * NH + h) * NQT2 + qt);
  const int row = wv * 16 + kl * 4;
#pragma unroll
  for (int r = 0; r < 4; ++r) {
    float* Op = Opart + (pbase * 128 + row + r) * HD;
#pragma unroll
    for (int di = 0; di < 8; ++di) Op[di * 16 + l16] = oacc[di][r];
    ml[(pbase * 2 + 0) * 128 + row + r] = mrow[r];
    ml[(pbase * 2 + 1) * 128 + row + r] = lrow[r];
  }
}

// ---------- merge partials (QBLK=128) -> bf16 O in Qb (unchanged, passing) ----------
__global__ __launch_bounds__(512) void attn_merge2_k(
    const float* __restrict__ Opart, const float* __restrict__ ml,
    unsigned short* __restrict__ Qb, int S) {
  const int qt = blockIdx.x, h = blockIdx.y;
  const int t = threadIdx.x;
  const int row = t >> 2, d0 = (t & 3) * 32;
  const int q = qt * 128 + row;

  float M = -1e30f;
  for (int s = 0; s < S; ++s) {
    const size_t pbase = (((size_t)s * NH + h) * NQT2 + qt);
    M = fmaxf(M, ml[(pbase * 2 + 0) * 128 + row]);
  }
  float L = 0.f;
  float o[32];
#pragma unroll
  for (int i = 0; i < 32; ++i) o[i] = 0.f;
  for (int s = 0; s < S; ++s) {
    const size_t pbase = (((size_t)s * NH + h) * NQT2 + qt);
    const float ms = ml[(pbase * 2 + 0) * 128 + row];
    const float ls = ml[(pbase * 2 + 1) * 128 + row];
    const float w = __expf(ms - M);
    L += w * ls;
    const float* Op = Opart + (pbase * 128 + row) * HD + d0;
#pragma unroll
    for (int c = 0; c < 8; ++c) {
      f32x4 v = *(const f32x4*)(Op + c * 4);
#pragma unroll
      for (int i = 0; i < 4; ++i) o[c * 4 + i] += w * v[i];
    }
  }
  if (q < SEQ) {
    const float inv = 1.f / L;
    unsigned short* op = Qb + ((size_t)h * SEQ + q) * HD + d0;
#pragma unroll
    for (int i = 0; i < 32; ++i) op[i] = f2b(o[i] * inv);
  }
}

// ---------- fallback single-pass attention (known-passing, untouched) ----------
__global__ __launch_bounds__(256) void attn_k(
    unsigned short* __restrict__ Qb, const unsigned short* __restrict__ Kn,
    const unsigned short* __restrict__ Vn, const float* __restrict__ Kc,
    const float* __restrict__ Vc) {
  __shared__ short Kl[64][136];
  __shared__ short Vt[128][72];
  __shared__ short Pl[4][16][72];
  const int h = blockIdx.y, qt = blockIdx.x;
  const int tid = threadIdx.x, wv = tid >> 6, l = tid & 63;
  const int l16 = l & 15, kl = l >> 4;
  const float SCALE = 0.08838834764831845f;

  int qrow = qt * 64 + wv * 16 + l16;
  if (qrow > SEQ - 1) qrow = SEQ - 1;
  bf16x8 qf[4];
#pragma unroll
  for (int kk = 0; kk < 4; ++kk)
    qf[kk] = *(const bf16x8*)(Qb + ((size_t)h * SEQ + qrow) * HD + kk * 32 + kl * 8);

  f32x4 oacc[8] = {};
  float mrow[4] = {-1e30f, -1e30f, -1e30f, -1e30f};
  float lrow[4] = {0.f, 0.f, 0.f, 0.f};

  for (int kv0 = 0; kv0 < LTOT; kv0 += 64) {
#pragma unroll
    for (int it = 0; it < 4; ++it) {
      int slot = tid + it * 256;
      int j = slot & 63, dq = slot >> 6;
      int jg = kv0 + j;
      bf16x8 kvv = {0,0,0,0,0,0,0,0}, vvv = {0,0,0,0,0,0,0,0};
      if (jg < NCACHE) {
        const float* kp = Kc + ((size_t)jg * NH + h) * HD + dq * 8;
        const float* vp = Vc + ((size_t)jg * NH + h) * HD + dq * 8;
        f32x4 ka = *(const f32x4*)(kp), kb = *(const f32x4*)(kp + 4);
        f32x4 va = *(const f32x4*)(vp), vb = *(const f32x4*)(vp + 4);
#pragma unroll
        for (int i = 0; i < 4; ++i) {
          kvv[i] = (short)f2b(ka[i]); kvv[4 + i] = (short)f2b(kb[i]);
          vvv[i] = (short)f2b(va[i]); vvv[4 + i] = (short)f2b(vb[i]);
        }
      } else if (jg < LTOT) {
        kvv = *(const bf16x8*)(Kn + ((size_t)h * SEQ + (jg - NCACHE)) * HD + dq * 8);
        vvv = *(const bf16x8*)(Vn + ((size_t)h * SEQ + (jg - NCACHE)) * HD + dq * 8);
      }
      *(bf16x8*)&Kl[j][dq * 8] = kvv;
#pragma unroll
      for (int i = 0; i < 8; ++i) Vt[dq * 8 + i][j] = vvv[i];
    }
    __syncthreads();

    f32x4 sa[4] = {};
#pragma unroll
    for (int ni = 0; ni < 4; ++ni)
#pragma unroll
      for (int kk = 0; kk < 4; ++kk) {
        bf16x8 bK = *(const bf16x8*)&Kl[ni * 16 + l16][kk * 32 + kl * 8];
        sa[ni] = __builtin_amdgcn_mfma_f32_16x16x32_bf16(qf[kk], bK, sa[ni], 0, 0, 0);
      }

    float sv[4][4];
    float pm[4] = {-1e30f, -1e30f, -1e30f, -1e30f};
#pragma unroll
    for (int ni = 0; ni < 4; ++ni) {
      int jg = kv0 + ni * 16 + l16;
      bool valid = jg < LTOT;
#pragma unroll
      for (int r = 0; r < 4; ++r) {
        float xs = valid ? sa[ni][r] * SCALE : -1e30f;
        sv[ni][r] = xs;
        pm[r] = fmaxf(pm[r], xs);
      }
    }
#pragma unroll
    for (int off = 1; off < 16; off <<= 1)
#pragma unroll
      for (int r = 0; r < 4; ++r) pm[r] = fmaxf(pm[r], __shfl_xor(pm[r], off));

    float sc[4];
#pragma unroll
    for (int r = 0; r < 4; ++r) {
      float mn = fmaxf(mrow[r], pm[r]);
      sc[r] = __expf(mrow[r] - mn);
      mrow[r] = mn;
    }
    float ps[4] = {0.f, 0.f, 0.f, 0.f};
#pragma unroll
    for (int ni = 0; ni < 4; ++ni)
#pragma unroll
      for (int r = 0; r < 4; ++r) {
        float p = __expf(sv[ni][r] - mrow[r]);
        sv[ni][r] = p;
        ps[r] += p;
      }
#pragma unroll
    for (int off = 1; off < 16; off <<= 1)
#pragma unroll
      for (int r = 0; r < 4; ++r) ps[r] += __shfl_xor(ps[r], off);
#pragma unroll
    for (int r = 0; r < 4; ++r) lrow[r] = lrow[r] * sc[r] + ps[r];
#pragma unroll
    for (int di = 0; di < 8; ++di)
#pragma unroll
      for (int r = 0; r < 4; ++r) oacc[di][r] *= sc[r];
#pragma unroll
    for (int ni = 0; ni < 4; ++ni)
#pragma unroll
      for (int r = 0; r < 4; ++r)
        Pl[wv][kl * 4 + r][ni * 16 + l16] = (short)f2b(sv[ni][r]);
    __syncthreads();

#pragma unroll
    for (int di = 0; di < 8; ++di)
#pragma unroll
      for (int k2 = 0; k2 < 2; ++k2) {
        bf16x8 aP = *(const bf16x8*)&Pl[wv][l16][k2 * 32 + kl * 8];
        bf16x8 bV = *(const bf16x8*)&Vt[di * 16 + l16][k2 * 32 + kl * 8];
        oacc[di] = __builtin_amdgcn_mfma_f32_16x16x32_bf16(aP, bV, oacc[di], 0, 0, 0);
      }
    __syncthreads();
  }

  const int qb = qt * 64 + wv * 16 + kl * 4;
#pragma unroll
  for (int r = 0; r < 4; ++r) {
    int q = qb + r;
    if (q < SEQ) {
      float inv = 1.0f / lrow[r];
#pragma unroll
      for (int di = 0; di < 8; ++di)
        Qb[((size_t)h * SEQ + q) * HD + di * 16 + l16] = f2b(oacc[di][r] * inv);
    }
  }
}

extern "C" void kernel_launch(void* const* d_in, const int* in_sizes, int n_in,
                              void* d_out, int out_size, void* d_ws, size_t ws_size,
                              hipStream_t stream) {
  const float* x  = (const float*)d_in[0];
  const float* fr = (const float*)d_in[2];
  const float* Kc = (const float*)d_in[3];
  const float* Vc = (const float*)d_in[4];
  const float* Wq = (const float*)d_in[5];
  const float* bq = (const float*)d_in[6];
  const float* Wk = (const float*)d_in[7];
  const float* bk = (const float*)d_in[8];
  const float* Wv = (const float*)d_in[9];
  const float* bv = (const float*)d_in[10];
  const float* Wo = (const float*)d_in[11];
  const float* bo = (const float*)d_in[12];
  const float* gq = (const float*)d_in[13];
  const float* gk = (const float*)d_in[14];

  unsigned short* Qb = (unsigned short*)d_ws;
  unsigned short* Kn = Qb + (size_t)NH * SEQ * HD;
  unsigned short* Vn = Kn + (size_t)NH * SEQ * HD;
  const size_t baseB = (size_t)3 * NH * SEQ * HD * 2;

  const size_t perSplitB = (size_t)NH * NQT2 * 128 * HD * 4
                         + (size_t)NH * NQT2 * 2 * 128 * 4;
  int S = 0;
  if (ws_size >= baseB + 8 * perSplitB + (1 << 20)) S = 8;
  else if (ws_size >= baseB + 7 * perSplitB + (1 << 20)) S = 7;
  else if (ws_size >= baseB + 4 * perSplitB + (1 << 20)) S = 4;

  gemm_qkv_k<<<dim3(48, 17), 256, 0, stream>>>(x, Wq, Wk, Wv, bq, bk, bv, Qb, Kn, Vn);
  rmsrope_k<<<dim3(SEQ, 2), 256, 0, stream>>>(Qb, Kn, gq, gk, fr);

  if (S > 0) {
    float* Opart = (float*)((char*)d_ws + baseB);
    float* ml    = Opart + (size_t)S * NH * NQT2 * 128 * HD;
    const int tiles = (LTOT + 63) / 64;                // 147
    const int chunk = ((tiles + S - 1) / S) * 64;
    attn_part2_k<<<dim3(NQT2 * NH * S), 512, 0, stream>>>(Qb, Kn, Vn, Kc, Vc, Opart, ml, chunk, S);
    attn_merge2_k<<<dim3(NQT2, NH), 512, 0, stream>>>(Opart, ml, Qb, S);
  } else {
    attn_k<<<dim3(NQT, NH), 256, 0, stream>>>(Qb, Kn, Vn, Kc, Vc);
  }

  gemm_k<<<dim3(16, 17), 256, 0, stream>>>(Qb, Wo, bo, d_out, 1, 3);
}